// Round 7
// baseline (161.829 us; speedup 1.0000x reference)
//
#include <hip/hip_runtime.h>
#include <stdint.h>

// All I/O fp32. MFMA bf16 path, weights as A-operand (A[m=out][k]), activations
// as B (B[k][n=point]). Layer->layer D->B handoff is in-lane only because each
// next layer's weights are pre-permuted along input dim:
//   P(k) = 4*(k>>3) + (k&3) + 16*((k>>2)&1)
// R4: weight frags staged to LDS; two independent 16-point groups (q) for ILP.
// R5 (FAILED): __launch_bounds__(256,4) -> 64 arch VGPR -> massive spill.
// R6: grid 1024: dur identical to R4 -> residency capped by TOTAL unified regs.
// R7: native cvt_pk packs: VALUBusy 27->18%, dur unchanged -> latency-bound.
// R8 (FAILED): two-kernel split; coeff handoff through out = HBM round-trip.
// R9: in-wave phase split: VGPR 84, Occ 20.4%, dur STILL 42 (3 resident vs
//   4 work-blocks/CU -> batching tail ate the residency gain).
// R10: grid 2048 + load hoist: Occ 22.7%, dur STILL 41. hbm_gbps pinned at
//   2000+-60 across FIVE structural variants -> either external HBM
//   contention (the ~3x268MB harness poison fills' writeback drain overlaps
//   us; per-rep total ~934MB/6TB/s ~= the scored 158us) or residency never
//   actually reached steady state (batching tails every time).
// R11 DECISIVE TEST: single-batch full residency. Bias LDS compacted
//   11KB -> 768B (broadcast float4 reads), per-iteration coeff strips
//   (removes LDS alias hazard). LDS 33.8KB -> 4 blocks/CU; grid 1024 =
//   exactly 4 work-blocks/CU; regs ~84 << 128 -> ALL 16 waves/CU resident,
//   zero tail. If dur stays ~41us at ~2x occupancy -> externally BW-capped
//   -> roofline. If it drops -> residency was the lever all along.

typedef __attribute__((ext_vector_type(8))) __bf16 bf16x8;
typedef __attribute__((ext_vector_type(2))) __bf16 bf16x2;
typedef __attribute__((ext_vector_type(4))) float f32x4;

union FragU { uint32_t u[4]; bf16x8 v; uint4 q; };

__device__ __forceinline__ unsigned short f2bf(float f) {
    union { float f; uint32_t i; } v; v.f = f;
    return (unsigned short)((v.i + 0x7FFFu + ((v.i >> 16) & 1u)) >> 16); // RTNE (prep only)
}
__device__ __forceinline__ float bf2f(uint32_t u16) {
    union { uint32_t i; float f; } v; v.i = u16 << 16; return v.f;
}
// native pack: compiler lowers cast pairs to v_cvt_pk_bf16_f32 (RTNE)
__device__ __forceinline__ uint32_t pk2(float x, float y) {
    union { bf16x2 h; uint32_t u; } c;
    c.h[0] = (__bf16)x; c.h[1] = (__bf16)y;
    return c.u;
}
__device__ __forceinline__ bf16x8 pack8(float a, float b, float c, float d,
                                        float e, float f, float g, float h) {
    bf16x8 v;
    v[0] = (__bf16)a; v[1] = (__bf16)b; v[2] = (__bf16)c; v[3] = (__bf16)d;
    v[4] = (__bf16)e; v[5] = (__bf16)f; v[6] = (__bf16)g; v[7] = (__bf16)h;
    return v;
}
__device__ __forceinline__ int permK(int k) {
    return 4 * (k >> 3) + (k & 3) + 16 * ((k >> 2) & 1);
}
__device__ __forceinline__ f32x4 MF(bf16x8 a, bf16x8 b, f32x4 c) {
    return __builtin_amdgcn_mfma_f32_16x16x32_bf16(a, b, c, 0, 0, 0);
}

// ws dword layout (7616 dwords):
//   [0,1024)    layer0 A-frags  [chunk(2)][tile(2)][lane(64)][dw(4)]  (K=60 pad 64)
//   [1024,3072) layers1-4 A     [L(4)][tile(2)][lane][dw]             (perm k)
//   [3072,3328) layer5 A        [lane][dw]                            (perm k, m>=8 zero)
//   [3328,7424) bank A          [k(8)][tile(2)][lane][dw]
//   [7424,7616) compact biases fp32 [L(6)][m(32)]                     (L5: m>=8 zero)

struct WPf { const float* p[13]; };

__global__ void pc_prep(WPf wp, uint32_t* __restrict__ ws) {
    int idx = blockIdx.x * blockDim.x + threadIdx.x;
    if (idx >= 7616) return;
    if (idx < 7424) {
        int layer, t, chunk = 0, lane, d; const float* w; bool perm;
        int r = idx;
        if (r < 1024) { chunk = r >> 9; r &= 511; t = r >> 8; r &= 255; lane = r >> 2; d = r & 3;
                        layer = 0; w = wp.p[0]; perm = false; }
        else if (r < 3072) { r -= 1024; layer = 1 + (r >> 9); r &= 511; t = r >> 8; r &= 255;
                             lane = r >> 2; d = r & 3; w = wp.p[2 * layer]; perm = true; }
        else if (r < 3328) { r -= 3072; layer = 5; t = 0; lane = r >> 2; d = r & 3;
                             w = wp.p[10]; perm = true; }
        else { r -= 3328; int bk = r >> 9; r &= 511; t = r >> 8; r &= 255; lane = r >> 2; d = r & 3;
               layer = -1; w = wp.p[12] + bk * 1024; perm = false; }
        int gq = lane >> 4, m = t * 16 + (lane & 15);
        uint32_t o = 0;
        #pragma unroll
        for (int e = 0; e < 2; ++e) {
            int kf = 8 * gq + 2 * d + e;
            float v = 0.f;
            if (layer == -1) {
                v = w[kf * 32 + m];                       // bank: A[m=o][k=i] = bank[k][i*32+o]
            } else {
                int ks = perm ? permK(kf) : (chunk * 32 + kf);
                if (layer == 0)      { if (ks < 60) v = w[ks * 32 + m]; }
                else if (layer == 5) { if (m < 8)   v = w[ks * 8 + m]; }
                else                 v = w[ks * 32 + m];  // A[m][k] = W[P(k)][m]
            }
            o |= ((uint32_t)f2bf(v)) << (16 * e);
        }
        ws[idx] = o;
    } else {
        int r = idx - 7424; int L = r >> 5, m = r & 31;
        float v;
        if (L < 5)      v = wp.p[2 * L + 1][m];
        else            v = (m < 8) ? wp.p[11][m] : 0.f;
        ((float*)ws)[idx] = v;
    }
}

// 32 points per wave-iteration (2 groups x 16), IT=2 -> 64 points/wave,
// 4 waves/block = 256 points/block, grid 1024 = exactly 4 blocks/CU.
#define IT 2

// W LDS dword map (8640 dwords = 33.75 KB -> 4 blocks/CU):
//   [0,7616)     frags + compact biases (== ws, linear copy)
//   [7616,8640)  coeffs: [it(2)][wave(4)][point(32)][4dw]
#define CO 7616

__global__ __launch_bounds__(256, 3) void pc_main(
    const float* __restrict__ rel, const float* __restrict__ feat,
    const uint32_t* __restrict__ wsu, float* __restrict__ out)
{
    __shared__ __align__(16) uint32_t W[8640];
    { // cooperative stage: 1904 x uint4, linear
        uint4* s4 = (uint4*)W;
        const uint4* g4 = (const uint4*)wsu;
        #pragma unroll
        for (int i = 0; i < 8; ++i) {
            int idx = threadIdx.x + 256 * i;
            if (idx < 1904) s4[idx] = g4[idx];
        }
    }
    __syncthreads();

    const int lane = threadIdx.x & 63;
    const int wv = threadIdx.x >> 6;
    const int g = lane >> 4;
    const int n16 = lane & 15;
    const size_t pt0 = (size_t)blockIdx.x * 256 + wv * 64;

    #define LDF(off) ({ FragU _f; _f.q = ((const uint4*)(W + (off)))[lane]; _f.v; })
    // compact bias: broadcast float4 (all 16 lanes of a g-group same address)
    #define LDB(L, t) ({ float4 _b = *(const float4*)((const float*)(W + 7424) + (L) * 32 + (t) * 16 + 4 * g); \
                         (f32x4){_b.x, _b.y, _b.z, _b.w}; })

    #pragma unroll
    for (int it = 0; it < IT; ++it) {
        const size_t nA = pt0 + it * 32 + n16;           // group 0 point; group 1 = +16
        const int cbase = CO + it * 512 + wv * 128;      // this wave's coeff strip

        // ---- global loads for this iteration (rel phase-1, feat phase-2) ----
        float4 ra[2], rb[2], rc[2], rd[2], fa[2], fb[2];
        #pragma unroll
        for (int q = 0; q < 2; ++q) {
            const float* rrow = rel + (nA + 16 * q) * 60;
            ra[q] = *(const float4*)(rrow + 8 * g);
            rb[q] = *(const float4*)(rrow + 8 * g + 4);
            rc[q] = *(const float4*)(rrow + 32 + 8 * g);
            rd[q] = make_float4(0.f, 0.f, 0.f, 0.f);
            if (g < 3) rd[q] = *(const float4*)(rrow + 36 + 8 * g);
            const float* frow = feat + (nA + 16 * q) * 32 + 8 * g;
            fa[q] = *(const float4*)frow;
            fb[q] = *(const float4*)(frow + 4);
        }

        // ================= Phase 1: MLP + softmax -> coeffs in LDS ==========
        {
            bf16x8 c0[2], c1[2];
            #pragma unroll
            for (int q = 0; q < 2; ++q) {
                c0[q] = pack8(ra[q].x, ra[q].y, ra[q].z, ra[q].w,
                              rb[q].x, rb[q].y, rb[q].z, rb[q].w);
                c1[q] = pack8(rc[q].x, rc[q].y, rc[q].z, rc[q].w,
                              rd[q].x, rd[q].y, rd[q].z, rd[q].w);
            }

            f32x4 t0[2], t1[2];
            {
                f32x4 ba = LDB(0, 0), bb = LDB(0, 1);
                bf16x8 w00 = LDF(0), w01 = LDF(256), w10 = LDF(512), w11 = LDF(768);
                #pragma unroll
                for (int q = 0; q < 2; ++q) {
                    t0[q] = MF(w00, c0[q], ba);    t1[q] = MF(w01, c0[q], bb);
                    t0[q] = MF(w10, c1[q], t0[q]); t1[q] = MF(w11, c1[q], t1[q]);
                }
            }

            // ---- layers 1..4: leaky -> in-lane pack -> mfma (perm weights) ----
            #pragma unroll
            for (int L = 0; L < 4; ++L) {
                bf16x8 wa = LDF(1024 + L * 512), wb = LDF(1024 + L * 512 + 256);
                f32x4 ba = LDB(L + 1, 0), bb = LDB(L + 1, 1);
                #pragma unroll
                for (int q = 0; q < 2; ++q) {
                    #pragma unroll
                    for (int r = 0; r < 4; ++r) {
                        t0[q][r] = fmaxf(t0[q][r], 0.01f * t0[q][r]);
                        t1[q][r] = fmaxf(t1[q][r], 0.01f * t1[q][r]);
                    }
                    bf16x8 bx = pack8(t0[q][0], t0[q][1], t0[q][2], t0[q][3],
                                      t1[q][0], t1[q][1], t1[q][2], t1[q][3]);
                    t0[q] = MF(wa, bx, ba);
                    t1[q] = MF(wb, bx, bb);
                }
            }

            // ---- layer5 (32->8) ----
            {
                bf16x8 w5 = LDF(3072);
                f32x4 b5 = LDB(5, 0);
                #pragma unroll
                for (int q = 0; q < 2; ++q) {
                    #pragma unroll
                    for (int r = 0; r < 4; ++r) {
                        t0[q][r] = fmaxf(t0[q][r], 0.01f * t0[q][r]);
                        t1[q][r] = fmaxf(t1[q][r], 0.01f * t1[q][r]);
                    }
                    bf16x8 bx = pack8(t0[q][0], t0[q][1], t0[q][2], t0[q][3],
                                      t1[q][0], t1[q][1], t1[q][2], t1[q][3]);
                    t0[q] = MF(w5, bx, b5);   // logits m0..3 in g=0, m4..7 in g=1
                }
            }

            // ---- softmax over 8 per point; g0 parks c0..3, g1 parks c4..7 ----
            #pragma unroll
            for (int q = 0; q < 2; ++q) {
                float m4 = fmaxf(fmaxf(t0[q][0], t0[q][1]), fmaxf(t0[q][2], t0[q][3]));
                float m8 = fmaxf(m4, __shfl_xor(m4, 16, 64));
                float e0 = __expf(t0[q][0] - m8), e1 = __expf(t0[q][1] - m8);
                float e2 = __expf(t0[q][2] - m8), e3 = __expf(t0[q][3] - m8);
                float s4 = e0 + e1 + e2 + e3;
                float s8 = s4 + __shfl_xor(s4, 16, 64);
                float inv = 1.0f / s8;
                uint32_t p01 = pk2(e0 * inv, e1 * inv);
                uint32_t p23 = pk2(e2 * inv, e3 * inv);
                if (g < 2)
                    *(uint2*)(W + cbase + (q * 16 + n16) * 4 + 2 * g) = make_uint2(p01, p23);
            }
        }

        // ================= Phase 2: bank stage (coeffs from LDS) ============
        {
            uint4 cp[2];
            #pragma unroll
            for (int q = 0; q < 2; ++q)
                cp[q] = *(const uint4*)(W + cbase + (q * 16 + n16) * 4);

            bf16x8 bfr[2];
            #pragma unroll
            for (int q = 0; q < 2; ++q)
                bfr[q] = pack8(fa[q].x, fa[q].y, fa[q].z, fa[q].w,
                               fb[q].x, fb[q].y, fb[q].z, fb[q].w);

            float cw[2][8];
            #pragma unroll
            for (int q = 0; q < 2; ++q) {
                cw[q][0] = bf2f(cp[q].x & 0xffff); cw[q][1] = bf2f(cp[q].x >> 16);
                cw[q][2] = bf2f(cp[q].y & 0xffff); cw[q][3] = bf2f(cp[q].y >> 16);
                cw[q][4] = bf2f(cp[q].z & 0xffff); cw[q][5] = bf2f(cp[q].z >> 16);
                cw[q][6] = bf2f(cp[q].w & 0xffff); cw[q][7] = bf2f(cp[q].w >> 16);
            }

            f32x4 o0[2], o1[2];
            #pragma unroll
            for (int q = 0; q < 2; ++q) {
                o0[q] = (f32x4){0.f, 0.f, 0.f, 0.f};
                o1[q] = (f32x4){0.f, 0.f, 0.f, 0.f};
            }
            #pragma unroll
            for (int k = 0; k < 8; ++k) {
                bf16x8 wk0 = LDF(3328 + k * 512), wk1 = LDF(3328 + k * 512 + 256);
                #pragma unroll
                for (int q = 0; q < 2; ++q) {
                    f32x4 z = {0.f, 0.f, 0.f, 0.f};
                    f32x4 u0 = MF(wk0, bfr[q], z);
                    f32x4 u1 = MF(wk1, bfr[q], z);
                    #pragma unroll
                    for (int r = 0; r < 4; ++r) {
                        o0[q][r] += cw[q][k] * u0[r];
                        o1[q][r] += cw[q][k] * u1[r];
                    }
                }
            }

            #pragma unroll
            for (int q = 0; q < 2; ++q) {
                float* orow = out + (nA + 16 * q) * 32;
                *(float4*)(orow + 4 * g)      = make_float4(o0[q][0], o0[q][1], o0[q][2], o0[q][3]);
                *(float4*)(orow + 16 + 4 * g) = make_float4(o1[q][0], o1[q][1], o1[q][2], o1[q][3]);
            }
        }
    }
    #undef LDF
    #undef LDB
}

extern "C" void kernel_launch(void* const* d_in, const int* in_sizes, int n_in,
                              void* d_out, int out_size, void* d_ws, size_t ws_size,
                              hipStream_t stream)
{
    const float* rel = (const float*)d_in[0];
    const float* feat = (const float*)d_in[1];
    WPf wp;
    for (int i = 0; i < 13; ++i) wp.p[i] = (const float*)d_in[2 + i];
    uint32_t* ws = (uint32_t*)d_ws;
    float* out = (float*)d_out;

    const int npts = in_sizes[0] / 60;                 // 262144
    const int nblocks = npts / 256;                    // 1024 = exactly 4 blocks/CU

    hipLaunchKernelGGL(pc_prep, dim3(30), dim3(256), 0, stream, wp, ws);
    hipLaunchKernelGGL(pc_main, dim3(nblocks), dim3(256), 0, stream, rel, feat, ws, out);
}